// Round 1
// baseline (270.084 us; speedup 1.0000x reference)
//
#include <hip/hip_runtime.h>

#define TPB 256
#define IPB 256
#define NITEMS (2048*128)

__global__ __launch_bounds__(TPB) void canadarm_kernel(
    const float* __restrict__ com_g,   // (B,H,3,7)
    const float* __restrict__ pose_g,  // (B,H,4,4,9)
    const float* __restrict__ jac_g,   // (B,H,6,7)
    float* __restrict__ out_g)         // (B,H,6,7)
{
    __shared__ float lds[IPB*63];      // per item: com[21] | pose_t[21] | jac[21], stride 63 (odd -> conflict-free)
    const int tid = threadIdx.x;
    const size_t item0 = (size_t)blockIdx.x * IPB;

    // ---- stage com_list: contiguous 21 floats/item ----
    {
        const float* src = com_g + item0*21;
        #pragma unroll
        for (int k = tid; k < IPB*21; k += TPB) {
            int it = k/21, off = k - it*21;
            lds[it*63 + off] = src[k];
        }
    }
    // ---- stage pose translations: element [r][3][l] at r*36+27+l within the 144-float block ----
    {
        const float* src = pose_g + item0*144;
        #pragma unroll
        for (int k = tid; k < IPB*21; k += TPB) {
            int it = k/21, idx = k - it*21;
            int r = idx/7, l = idx - r*7;
            lds[it*63 + 21 + idx] = src[it*144 + r*36 + 27 + l];
        }
    }
    // ---- stage jacobian rows 0..2: first 21 floats of each 42-float block ----
    {
        const float* src = jac_g + item0*42;
        #pragma unroll
        for (int k = tid; k < IPB*21; k += TPB) {
            int it = k/21, off = k - it*21;
            lds[it*63 + 42 + off] = src[it*42 + off];
        }
    }
    __syncthreads();

    // ---- copy own item's 63 floats to registers ----
    float com[3][7], pp[3][7], J[3][7];
    {
        const float* L = lds + tid*63;
        #pragma unroll
        for (int c = 0; c < 3; ++c)
            #pragma unroll
            for (int i = 0; i < 7; ++i) {
                com[c][i] = L[c*7 + i];
                pp[c][i]  = L[21 + c*7 + i];
                J[c][i]   = L[42 + c*7 + i];
            }
    }
    __syncthreads();   // all staged reads done; LDS reusable for output staging

    // ---- constants (compiler const-folds all of this) ----
    const float mass[7] = {105.98f,105.98f,314.98f,279.2f,105.98f,105.98f,243.66f};
    const float diag[7][3] = {
        {12.19f,12.19f,3.061f},
        {12.19f,12.19f,3.061f},
        {15.41f,2094.71f,2103.19f},
        {9.522f,1966.28f,1966.28f},
        {8.305f,3.061f,8.0386f},
        {12.13f,12.13f,3.061f},
        {9.336f,44.41f,44.41f}};
    float msum = 0.f;
    #pragma unroll
    for (int i = 0; i < 7; ++i) msum += mass[i];
    const float M_total = msum + 100000.0f + 243.66f;
    const float inv_M   = 1.0f / M_total;
    const float bcz     = 6.65f * (243.66f / (100000.0f + 243.66f));
    float Cd[3];
    #pragma unroll
    for (int a = 0; a < 3; ++a) {
        float s0 = 0.f;
        #pragma unroll
        for (int i = 0; i < 7; ++i) s0 += diag[i][a];
        Cd[a] = s0;
    }
    Cd[0] += 69585.02f; Cd[1] += 69585.02f; Cd[2] += 66666.664f;
    const float Kc = M_total - msum;   // total_mass - sum(mass)

    // ---- system COM, r_og ----
    float rg[3];
    #pragma unroll
    for (int c = 0; c < 3; ++c) {
        float s0 = 0.f;
        #pragma unroll
        for (int i = 0; i < 7; ++i) s0 += com[c][i]*mass[i];
        rg[c] = s0 * inv_M;
    }
    rg[2] -= bcz;

    // ---- rp = com - pose_t, roi = com - base_com ----
    float rp[3][7], roi[3][7];
    #pragma unroll
    for (int i = 0; i < 7; ++i) {
        rp[0][i]  = com[0][i] - pp[0][i];
        rp[1][i]  = com[1][i] - pp[1][i];
        rp[2][i]  = com[2][i] - pp[2][i];
        roi[0][i] = com[0][i];
        roi[1][i] = com[1][i];
        roi[2][i] = com[2][i] - bcz;
    }

    // ---- suffix loop j = 6..0: builds w, s, M suffix sums; emits J_tw and H_theta columns ----
    // J_tw[:,j]  = J_j x w_j,            w_j = sum_{i>=j} m_i rp_i
    // Hwp2[:,j]  = J_j*s_j - M_j @ J_j,  s_j = sum m_i (roi_i . rp_i),  M_j = sum m_i rp_i roi_i^T
    // Hth[:,j]   = Dsuf_j o J_j + Hwp2[:,j] - rg x J_tw[:,j]
    float w0=0.f,w1=0.f,w2=0.f, ssum=0.f;
    float M00=0.f,M01=0.f,M02=0.f,M10=0.f,M11=0.f,M12=0.f,M20=0.f,M21=0.f,M22=0.f;
    float Ds0=0.f, Ds1=0.f, Ds2=0.f;
    float Jtw[3][7], Hth[3][7];
    #pragma unroll
    for (int j = 6; j >= 0; --j) {
        const float mi = mass[j];
        const float ax=rp[0][j],  ay=rp[1][j],  az=rp[2][j];
        const float bx=roi[0][j], by=roi[1][j], bz=roi[2][j];
        w0 += mi*ax; w1 += mi*ay; w2 += mi*az;
        ssum += mi*(ax*bx + ay*by + az*bz);
        M00 += mi*ax*bx; M01 += mi*ax*by; M02 += mi*ax*bz;
        M10 += mi*ay*bx; M11 += mi*ay*by; M12 += mi*ay*bz;
        M20 += mi*az*bx; M21 += mi*az*by; M22 += mi*az*bz;
        Ds0 += diag[j][0]; Ds1 += diag[j][1]; Ds2 += diag[j][2];

        const float jx=J[0][j], jy=J[1][j], jz=J[2][j];
        const float tx = jy*w2 - jz*w1;
        const float ty = jz*w0 - jx*w2;
        const float tz = jx*w1 - jy*w0;
        Jtw[0][j]=tx; Jtw[1][j]=ty; Jtw[2][j]=tz;

        const float h2x = jx*ssum - (M00*jx + M01*jy + M02*jz);
        const float h2y = jy*ssum - (M10*jx + M11*jy + M12*jz);
        const float h2z = jz*ssum - (M20*jx + M21*jy + M22*jz);

        const float cx = rg[1]*tz - rg[2]*ty;
        const float cy = rg[2]*tx - rg[0]*tz;
        const float cz = rg[0]*ty - rg[1]*tx;

        Hth[0][j] = Ds0*jx + h2x - cx;
        Hth[1][j] = Ds1*jy + h2y - cy;
        Hth[2][j] = Ds2*jz + h2z - cz;
    }

    // ---- H_s (symmetric) = Cd*I + Kc*(r r^T - r^2 I); analytic symmetric inverse ----
    const float r2 = rg[0]*rg[0] + rg[1]*rg[1] + rg[2]*rg[2];
    const float Hs00 = Kc*(rg[0]*rg[0] - r2) + Cd[0];
    const float Hs11 = Kc*(rg[1]*rg[1] - r2) + Cd[1];
    const float Hs22 = Kc*(rg[2]*rg[2] - r2) + Cd[2];
    const float Hs01 = Kc*rg[0]*rg[1];
    const float Hs02 = Kc*rg[0]*rg[2];
    const float Hs12 = Kc*rg[1]*rg[2];
    const float A = Hs11*Hs22 - Hs12*Hs12;
    const float B = Hs12*Hs02 - Hs01*Hs22;
    const float C = Hs01*Hs12 - Hs11*Hs02;
    const float det = Hs00*A + Hs01*B + Hs02*C;
    const float id_ = 1.0f/det;
    const float Hi00 = A*id_, Hi01 = B*id_, Hi02 = C*id_;
    const float Hi11 = (Hs00*Hs22 - Hs02*Hs02)*id_;
    const float Hi12 = (Hs02*Hs01 - Hs00*Hs12)*id_;
    const float Hi22 = (Hs00*Hs11 - Hs01*Hs01)*id_;

    // ---- output columns, written straight into LDS (stride 43, odd -> conflict-free) ----
    float* O = lds + tid*43;
    #pragma unroll
    for (int j = 0; j < 7; ++j) {
        const float hx=Hth[0][j], hy=Hth[1][j], hz=Hth[2][j];
        const float vx = Hi00*hx + Hi01*hy + Hi02*hz;
        const float vy = Hi01*hx + Hi11*hy + Hi12*hz;
        const float vz = Hi02*hx + Hi12*hy + Hi22*hz;
        const float bx = -vx, by = -vy, bz = -vz;
        O[0*7+j] = -Jtw[0][j]*inv_M + (rg[1]*bz - rg[2]*by);
        O[1*7+j] = -Jtw[1][j]*inv_M + (rg[2]*bx - rg[0]*bz);
        O[2*7+j] = -Jtw[2][j]*inv_M + (rg[0]*by - rg[1]*bx);
        O[3*7+j] = bx;
        O[4*7+j] = by;
        O[5*7+j] = bz;
    }
    __syncthreads();

    // ---- coalesced output store ----
    {
        float* dst = out_g + item0*42;
        #pragma unroll
        for (int k = tid; k < IPB*42; k += TPB) {
            int it = k/42, off = k - it*42;
            dst[k] = lds[it*43 + off];
        }
    }
}

extern "C" void kernel_launch(void* const* d_in, const int* in_sizes, int n_in,
                              void* d_out, int out_size, void* d_ws, size_t ws_size,
                              hipStream_t stream) {
    const float* com  = (const float*)d_in[0];
    const float* pose = (const float*)d_in[1];
    const float* jac  = (const float*)d_in[2];
    float* out = (float*)d_out;
    dim3 grid(NITEMS/IPB), block(TPB);
    hipLaunchKernelGGL(canadarm_kernel, grid, block, 0, stream, com, pose, jac, out);
}

// Round 2
// 264.636 us; speedup vs baseline: 1.0206x; 1.0206x over previous
//
#include <hip/hip_runtime.h>

#define TPB 64
#define IPB 64
#define NITEMS (2048*128)

// LDS float layout (all regions stride-21 per item -> odd stride, conflict-free)
#define COM0  0            // [it][off<21] <- com_g identity
#define JAC0  (IPB*21)     // [it][off<21] <- jac_g[it*42 + off]
#define POSE0 (2*IPB*21)   // [it][r*7+l]  <- pose_g[it*144 + r*36 + 27 + l]
#define LDS_FLOATS (3*IPB*21)

__device__ __forceinline__ void gload4(void* lds_dst, const void* gsrc) {
    __builtin_amdgcn_global_load_lds((const __attribute__((address_space(1))) void*)gsrc,
                                     (__attribute__((address_space(3))) void*)lds_dst, 4, 0, 0);
}
__device__ __forceinline__ void gload16(void* lds_dst, const void* gsrc) {
    __builtin_amdgcn_global_load_lds((const __attribute__((address_space(1))) void*)gsrc,
                                     (__attribute__((address_space(3))) void*)lds_dst, 16, 0, 0);
}

__global__ __launch_bounds__(TPB) void canadarm_kernel(
    const float* __restrict__ com_g,   // (B,H,3,7)
    const float* __restrict__ pose_g,  // (B,H,4,4,9)
    const float* __restrict__ jac_g,   // (B,H,6,7)
    float* __restrict__ out_g)         // (B,H,6,7)
{
    __shared__ float sh[LDS_FLOATS];   // 16,128 B -> 10 blocks/CU
    const int tid = threadIdx.x;
    const size_t item0 = (size_t)blockIdx.x * IPB;

    // ---- async stage com: identity map, width-16 for bulk ----
    {
        const float* src = com_g + item0*21;          // 16B-aligned (84*64 % 16 == 0)
        #pragma unroll
        for (int i = 0; i < 5; ++i) {                 // 320 float4 slots of 336
            int s4 = tid + i*64;
            gload16(&sh[COM0 + (size_t)i*256], src + (size_t)s4*4);
        }
        // tail: floats 1280..1343
        gload4(&sh[COM0 + 1280], src + 1280 + tid);
    }
    // ---- async stage jac rows 0..2: lds[it*21+off] <- g[it*42+off] ----
    {
        const float* src = jac_g + item0*42;
        #pragma unroll
        for (int i = 0; i < 21; ++i) {
            int t  = tid + i*64;
            int it = t / 21;
            int off = t - it*21;
            gload4(&sh[JAC0 + i*64], src + it*42 + off);
        }
    }
    // ---- async stage pose translations: lds[it*21+r*7+l] <- g[it*144+r*36+27+l] ----
    {
        const float* src = pose_g + item0*144;
        #pragma unroll
        for (int i = 0; i < 21; ++i) {
            int t   = tid + i*64;
            int it  = t / 21;
            int idx = t - it*21;
            int r   = idx / 7;
            int l   = idx - r*7;
            gload4(&sh[POSE0 + i*64], src + it*144 + r*36 + 27 + l);
        }
    }
    __syncthreads();   // drains vmcnt(0) then barrier -> single latency exposure

    // ---- copy own item's 63 floats to registers (stride 21: conflict-free) ----
    float com[3][7], pp[3][7], J[3][7];
    {
        const float* Lc = sh + COM0  + tid*21;
        const float* Lj = sh + JAC0  + tid*21;
        const float* Lp = sh + POSE0 + tid*21;
        #pragma unroll
        for (int c = 0; c < 3; ++c)
            #pragma unroll
            for (int i = 0; i < 7; ++i) {
                com[c][i] = Lc[c*7 + i];
                J[c][i]   = Lj[c*7 + i];
                pp[c][i]  = Lp[c*7 + i];
            }
    }

    // ---- constants ----
    const float mass[7] = {105.98f,105.98f,314.98f,279.2f,105.98f,105.98f,243.66f};
    const float diag[7][3] = {
        {12.19f,12.19f,3.061f},
        {12.19f,12.19f,3.061f},
        {15.41f,2094.71f,2103.19f},
        {9.522f,1966.28f,1966.28f},
        {8.305f,3.061f,8.0386f},
        {12.13f,12.13f,3.061f},
        {9.336f,44.41f,44.41f}};
    float msum = 0.f;
    #pragma unroll
    for (int i = 0; i < 7; ++i) msum += mass[i];
    const float M_total = msum + 100000.0f + 243.66f;
    const float inv_M   = 1.0f / M_total;
    const float bcz     = 6.65f * (243.66f / (100000.0f + 243.66f));
    float Cd[3];
    #pragma unroll
    for (int a = 0; a < 3; ++a) {
        float s0 = 0.f;
        #pragma unroll
        for (int i = 0; i < 7; ++i) s0 += diag[i][a];
        Cd[a] = s0;
    }
    Cd[0] += 69585.02f; Cd[1] += 69585.02f; Cd[2] += 66666.664f;
    const float Kc = M_total - msum;

    // ---- system COM, r_og ----
    float rg[3];
    #pragma unroll
    for (int c = 0; c < 3; ++c) {
        float s0 = 0.f;
        #pragma unroll
        for (int i = 0; i < 7; ++i) s0 += com[c][i]*mass[i];
        rg[c] = s0 * inv_M;
    }
    rg[2] -= bcz;

    float rp[3][7], roi[3][7];
    #pragma unroll
    for (int i = 0; i < 7; ++i) {
        rp[0][i]  = com[0][i] - pp[0][i];
        rp[1][i]  = com[1][i] - pp[1][i];
        rp[2][i]  = com[2][i] - pp[2][i];
        roi[0][i] = com[0][i];
        roi[1][i] = com[1][i];
        roi[2][i] = com[2][i] - bcz;
    }

    // ---- suffix loop j = 6..0 ----
    float w0=0.f,w1=0.f,w2=0.f, ssum=0.f;
    float M00=0.f,M01=0.f,M02=0.f,M10=0.f,M11=0.f,M12=0.f,M20=0.f,M21=0.f,M22=0.f;
    float Ds0=0.f, Ds1=0.f, Ds2=0.f;
    float Jtw[3][7], Hth[3][7];
    #pragma unroll
    for (int j = 6; j >= 0; --j) {
        const float mi = mass[j];
        const float ax=rp[0][j],  ay=rp[1][j],  az=rp[2][j];
        const float bx=roi[0][j], by=roi[1][j], bz=roi[2][j];
        w0 += mi*ax; w1 += mi*ay; w2 += mi*az;
        ssum += mi*(ax*bx + ay*by + az*bz);
        M00 += mi*ax*bx; M01 += mi*ax*by; M02 += mi*ax*bz;
        M10 += mi*ay*bx; M11 += mi*ay*by; M12 += mi*ay*bz;
        M20 += mi*az*bx; M21 += mi*az*by; M22 += mi*az*bz;
        Ds0 += diag[j][0]; Ds1 += diag[j][1]; Ds2 += diag[j][2];

        const float jx=J[0][j], jy=J[1][j], jz=J[2][j];
        const float tx = jy*w2 - jz*w1;
        const float ty = jz*w0 - jx*w2;
        const float tz = jx*w1 - jy*w0;
        Jtw[0][j]=tx; Jtw[1][j]=ty; Jtw[2][j]=tz;

        const float h2x = jx*ssum - (M00*jx + M01*jy + M02*jz);
        const float h2y = jy*ssum - (M10*jx + M11*jy + M12*jz);
        const float h2z = jz*ssum - (M20*jx + M21*jy + M22*jz);

        const float cx = rg[1]*tz - rg[2]*ty;
        const float cy = rg[2]*tx - rg[0]*tz;
        const float cz = rg[0]*ty - rg[1]*tx;

        Hth[0][j] = Ds0*jx + h2x - cx;
        Hth[1][j] = Ds1*jy + h2y - cy;
        Hth[2][j] = Ds2*jz + h2z - cz;
    }

    // ---- H_s symmetric inverse ----
    const float r2 = rg[0]*rg[0] + rg[1]*rg[1] + rg[2]*rg[2];
    const float Hs00 = Kc*(rg[0]*rg[0] - r2) + Cd[0];
    const float Hs11 = Kc*(rg[1]*rg[1] - r2) + Cd[1];
    const float Hs22 = Kc*(rg[2]*rg[2] - r2) + Cd[2];
    const float Hs01 = Kc*rg[0]*rg[1];
    const float Hs02 = Kc*rg[0]*rg[2];
    const float Hs12 = Kc*rg[1]*rg[2];
    const float A = Hs11*Hs22 - Hs12*Hs12;
    const float B = Hs12*Hs02 - Hs01*Hs22;
    const float C = Hs01*Hs12 - Hs11*Hs02;
    const float det = Hs00*A + Hs01*B + Hs02*C;
    const float id_ = 1.0f/det;
    const float Hi00 = A*id_, Hi01 = B*id_, Hi02 = C*id_;
    const float Hi11 = (Hs00*Hs22 - Hs02*Hs02)*id_;
    const float Hi12 = (Hs02*Hs01 - Hs00*Hs12)*id_;
    const float Hi22 = (Hs00*Hs11 - Hs01*Hs01)*id_;

    __syncthreads();   // all input LDS reads done; reuse LDS for output

    // ---- output into LDS, stride 42 (linear slot order; 4-way write conflict ~free) ----
    float* O = sh + tid*42;
    #pragma unroll
    for (int j = 0; j < 7; ++j) {
        const float hx=Hth[0][j], hy=Hth[1][j], hz=Hth[2][j];
        const float vx = Hi00*hx + Hi01*hy + Hi02*hz;
        const float vy = Hi01*hx + Hi11*hy + Hi12*hz;
        const float vz = Hi02*hx + Hi12*hy + Hi22*hz;
        const float bx = -vx, by = -vy, bz = -vz;
        O[0*7+j] = -Jtw[0][j]*inv_M + (rg[1]*bz - rg[2]*by);
        O[1*7+j] = -Jtw[1][j]*inv_M + (rg[2]*bx - rg[0]*bz);
        O[2*7+j] = -Jtw[2][j]*inv_M + (rg[0]*by - rg[1]*bx);
        O[3*7+j] = bx;
        O[4*7+j] = by;
        O[5*7+j] = bz;
    }
    __syncthreads();

    // ---- coalesced float2 store (out base 8B-aligned: 168*64*blk) ----
    {
        const float2* so = (const float2*)sh;
        float2* dst = (float2*)(out_g + item0*42);
        #pragma unroll
        for (int i = 0; i < 21; ++i) {
            int p = tid + i*64;
            dst[p] = so[p];
        }
    }
}

extern "C" void kernel_launch(void* const* d_in, const int* in_sizes, int n_in,
                              void* d_out, int out_size, void* d_ws, size_t ws_size,
                              hipStream_t stream) {
    const float* com  = (const float*)d_in[0];
    const float* pose = (const float*)d_in[1];
    const float* jac  = (const float*)d_in[2];
    float* out = (float*)d_out;
    dim3 grid(NITEMS/IPB), block(TPB);
    hipLaunchKernelGGL(canadarm_kernel, grid, block, 0, stream, com, pose, jac, out);
}